// Round 2
// baseline (197.412 us; speedup 1.0000x reference)
//
#include <hip/hip_runtime.h>
#include <cstdint>
#include <cstddef>

typedef __attribute__((ext_vector_type(8))) short short8;
typedef __attribute__((ext_vector_type(4))) float f32x4;

#define MFMA16(a,b,c) __builtin_amdgcn_mfma_f32_16x16x32_bf16((a),(b),(c),0,0,0)

static __device__ __forceinline__ unsigned short f2bf(float f) {
  union { float f; unsigned u; } v; v.f = f;
  unsigned r = v.u + 0x7fffu + ((v.u >> 16) & 1u);
  return (unsigned short)(r >> 16);
}
static __device__ __forceinline__ float bf2f(unsigned short h) {
  union { unsigned u; float f; } v; v.u = ((unsigned)h) << 16;
  return v.f;
}

// ---------------- K0: weights f32 -> bf16 ----------------
__global__ __launch_bounds__(256) void k_wcvt(const float* __restrict__ w_val,
                                              const float* __restrict__ w_red,
                                              unsigned short* __restrict__ wv,
                                              unsigned short* __restrict__ wr) {
  int i = blockIdx.x * 256 + threadIdx.x;
  if (i < 65536) wv[i] = f2bf(w_val[i]);
  int j = i - 65536;
  if (j >= 0 && j < 8192) wr[j] = f2bf(w_red[j]);
}

// ---------------- K1: fused transpose + A/sq + val ----------------
// One WG per (p-tile of 64, batch). Stages feat[c][p-tile] into LDS as bf16 [p][c],
// then computes val = relu(w_val@feat+b) for all 256 c, and A = relu(feat^T@w_red^T+b), sq.
__global__ __launch_bounds__(512) void k_prep(const float* __restrict__ feat,
                                              const unsigned short* __restrict__ wv,
                                              const unsigned short* __restrict__ wr,
                                              const float* __restrict__ b_red,
                                              const float* __restrict__ b_val,
                                              unsigned short* __restrict__ A,
                                              float* __restrict__ sq,
                                              unsigned short* __restrict__ val) {
  __shared__ unsigned short smT[64][264];  // row stride 528B = 33 x 16B (odd) -> conflict-free b128 reads
  __shared__ float sqp[2][64];
  const int t = threadIdx.x, w = t >> 6, lane = t & 63, a = lane & 15, g = lane >> 4;
  const int b = blockIdx.y, p0 = blockIdx.x * 64;
  const float* fb = feat + (size_t)b * 256 * 4096;
  // stage: thread reads 4 c-rows (consecutive c) at its p column, packs, one b64 LDS write
#pragma unroll
  for (int it = 0; it < 8; ++it) {
    int c0 = w * 4 + it * 32;
    const float* src = fb + (size_t)c0 * 4096 + p0 + lane;
    unsigned short u0 = f2bf(src[0]);
    unsigned short u1 = f2bf(src[4096]);
    unsigned short u2 = f2bf(src[8192]);
    unsigned short u3 = f2bf(src[12288]);
    uint2 pk;
    pk.x = u0 | ((unsigned)u1 << 16);
    pk.y = u2 | ((unsigned)u3 << 16);
    *(uint2*)&smT[lane][c0] = pk;
  }
  __syncthreads();

  f32x4 accv[2][4] = {};
  const int rs = w & 1, rms = w >> 1;  // red split: ci-half rs, p-subtile rms
  f32x4 accr = {0, 0, 0, 0};
#pragma unroll
  for (int kk = 0; kk < 8; ++kk) {
    short8 bfr[4];
#pragma unroll
    for (int ms = 0; ms < 4; ++ms)
      bfr[ms] = *(const short8*)&smT[ms * 16 + a][kk * 32 + g * 8];
#pragma unroll
    for (int s = 0; s < 2; ++s) {
      short8 af = *(const short8*)&wv[(w * 32 + s * 16 + a) * 256 + kk * 32 + g * 8];
#pragma unroll
      for (int ms = 0; ms < 4; ++ms)
        accv[s][ms] = MFMA16(af, bfr[ms], accv[s][ms]);
    }
    short8 wrf = *(const short8*)&wr[(rs * 16 + a) * 256 + kk * 32 + g * 8];
    accr = MFMA16(bfr[rms], wrf, accr);
  }
  // val epilogue
#pragma unroll
  for (int s = 0; s < 2; ++s) {
    f32x4 bv = *(const f32x4*)&b_val[w * 32 + s * 16 + g * 4];
#pragma unroll
    for (int ms = 0; ms < 4; ++ms) {
#pragma unroll
      for (int r = 0; r < 4; ++r) {
        float v = accv[s][ms][r] + bv[r];
        v = v > 0.f ? v : 0.f;
        int o = w * 32 + s * 16 + g * 4 + r;
        val[((size_t)(b * 256 + o)) * 4096 + p0 + ms * 16 + a] = f2bf(v);
      }
    }
  }
  // red epilogue: A rows p = p0 + rms*16 + g*4+r, cols ci = rs*16 + a
  float bias = b_red[rs * 16 + a];
  float rsum[4];
  unsigned short* Ab = A + ((size_t)b * 4096 + p0 + rms * 16) * 32;
#pragma unroll
  for (int r = 0; r < 4; ++r) {
    float v = accr[r] + bias;
    v = v > 0.f ? v : 0.f;
    unsigned short h = f2bf(v);
    Ab[(g * 4 + r) * 32 + rs * 16 + a] = h;
    float vb = bf2f(h);
    rsum[r] = vb * vb;
  }
#pragma unroll
  for (int off = 1; off < 16; off <<= 1) {
#pragma unroll
    for (int r = 0; r < 4; ++r) rsum[r] += __shfl_xor(rsum[r], off, 64);
  }
  if (a == 0) {
#pragma unroll
    for (int r = 0; r < 4; ++r) sqp[rs][rms * 16 + g * 4 + r] = rsum[r];
  }
  __syncthreads();
  if (t < 64) sq[(size_t)b * 4096 + p0 + t] = sqp[0][t] + sqp[1][t];
}

// ---------------- K2: fused mask + (val @ mask) + residual ----------------
// grid 512 WGs (128 m-tiles of 32 x 4 b), 512 thr, 2 WG/CU. Wave w: S-subtile
// (nsub=w&3, msub=w>>2), GEMM2 rows c in [32w, 32w+32). Mask stored at [m][n]
// (symmetric) with f32x4. LDS barrier waits lgkmcnt only (no vmcnt drain).
__global__ __launch_bounds__(512, 4) void k_fused(const unsigned short* __restrict__ A,
                                                  const float* __restrict__ sq,
                                                  const unsigned short* __restrict__ val,
                                                  const float* __restrict__ feat,
                                                  float* __restrict__ dout) {
  __shared__ unsigned short ldsT[2][32][72];  // [buf][m][n], stride 144B = 9 x 16B (odd)
  const int t = threadIdx.x, w = t >> 6, lane = t & 63, a = lane & 15, g = lane >> 4;
  const int nsub = w & 3, msub = w >> 2;
  // bijective XCD swizzle: 512 blocks, 64 contiguous per XCD -> each XCD's L2 sees one batch's val
  const int lin = blockIdx.x + 128 * blockIdx.y;
  const int swz = (lin & 7) * 64 + (lin >> 3);
  const int b = swz >> 7, m0 = (swz & 127) * 32;
  const unsigned short* Ab = A + (size_t)b * 4096 * 32;
  const float* sqb = sq + (size_t)b * 4096;
  const int mrow = m0 + msub * 16 + a;
  short8 am = *(const short8*)&Ab[(size_t)mrow * 32 + g * 8];
  // sqm in-register from the am fragment (reduce over g)
  float sm_ = 0.f;
#pragma unroll
  for (int j = 0; j < 8; ++j) { float x = bf2f((unsigned short)am[j]); sm_ += x * x; }
  sm_ += __shfl_xor(sm_, 16, 64);
  sm_ += __shfl_xor(sm_, 32, 64);
  const float sqm = sm_;
  f32x4 acc[2][2] = {};
  float* maskout = dout + 4194304 + (size_t)b * 16777216;
  const unsigned short* vb = val + ((size_t)b * 256 + w * 32) * 4096;

#pragma unroll 2
  for (int tt = 0; tt < 64; ++tt) {
    const int n0 = tt * 64, buf = tt & 1;
    short8 an = *(const short8*)&Ab[(size_t)(n0 + nsub * 16 + a) * 32 + g * 8];
    f32x4 sqn = *(const f32x4*)&sqb[n0 + nsub * 16 + g * 4];
    short8 vf[2][2];
#pragma unroll
    for (int cs = 0; cs < 2; ++cs)
#pragma unroll
      for (int ks = 0; ks < 2; ++ks)
        vf[cs][ks] = *(const short8*)&vb[(size_t)(cs * 16 + a) * 4096 + n0 + ks * 32 + g * 8];
    f32x4 zero = {0, 0, 0, 0};
    f32x4 sfr = MFMA16(an, am, zero);  // S[n=g*4+r][m=a]
    f32x4 mkv;
#pragma unroll
    for (int r = 0; r < 4; ++r) {
      float u = __expf(fmaf(2.f, sfr[r], -(sqn[r] + sqm)));  // exp(-D), in (0,1]
      // sigmoid(u) poly on [0,1], |err| <= 2.2e-4
      float u2 = u * u;
      float pa = fmaf(u2, 2.0833333e-3f, -2.0833333e-2f);
      float pb = fmaf(u2, pa, 0.25f);
      mkv[r] = fmaf(u, pb, 0.5f);
    }
    // LDS tile [m][n] bf16 for GEMM2 B-fragments
    uint2 pk;
    pk.x = f2bf(mkv[0]) | ((unsigned)f2bf(mkv[1]) << 16);
    pk.y = f2bf(mkv[2]) | ((unsigned)f2bf(mkv[3]) << 16);
    *(uint2*)&ldsT[buf][msub * 16 + a][nsub * 16 + g * 4] = pk;
    // symmetric mask store at [m][n]: one f32x4, stays in flight (never drained in-loop)
    *(f32x4*)&maskout[(size_t)mrow * 4096 + n0 + nsub * 16 + g * 4] = mkv;
    // LDS-only barrier: no vmcnt drain
    asm volatile("s_waitcnt lgkmcnt(0)\n\ts_barrier" ::: "memory");
#pragma unroll
    for (int ks = 0; ks < 2; ++ks) {
      short8 bfr0 = *(const short8*)&ldsT[buf][a][ks * 32 + g * 8];
      short8 bfr1 = *(const short8*)&ldsT[buf][16 + a][ks * 32 + g * 8];
#pragma unroll
      for (int cs = 0; cs < 2; ++cs) {
        acc[cs][0] = MFMA16(vf[cs][ks], bfr0, acc[cs][0]);
        acc[cs][1] = MFMA16(vf[cs][ks], bfr1, acc[cs][1]);
      }
    }
  }
  // epilogue: out = acc + features
  const float* fb = feat + (size_t)b * 256 * 4096;
  float* ob = dout + (size_t)b * 256 * 4096;
#pragma unroll
  for (int cs = 0; cs < 2; ++cs) {
#pragma unroll
    for (int ms = 0; ms < 2; ++ms) {
#pragma unroll
      for (int r = 0; r < 4; ++r) {
        int c = w * 32 + cs * 16 + g * 4 + r;
        int m = m0 + ms * 16 + a;
        size_t idx = (size_t)c * 4096 + m;
        ob[idx] = acc[cs][ms][r] + fb[idx];
      }
    }
  }
}

extern "C" void kernel_launch(void* const* d_in, const int* in_sizes, int n_in,
                              void* d_out, int out_size, void* d_ws, size_t ws_size,
                              hipStream_t stream) {
  const float* feat  = (const float*)d_in[0];
  const float* w_red = (const float*)d_in[1];
  const float* b_red = (const float*)d_in[2];
  const float* w_val = (const float*)d_in[3];
  const float* b_val = (const float*)d_in[4];
  float* out = (float*)d_out;
  char* ws = (char*)d_ws;
  unsigned short* A   = (unsigned short*)ws;               // 1,048,576 B
  float*          sq  = (float*)        (ws + 1048576);    //    65,536 B
  unsigned short* wv  = (unsigned short*)(ws + 1114112);   //   131,072 B
  unsigned short* wr  = (unsigned short*)(ws + 1245184);   //    16,384 B
  unsigned short* val = (unsigned short*)(ws + 1261568);   // 8,388,608 B

  k_wcvt<<<dim3(288), 256, 0, stream>>>(w_val, w_red, wv, wr);
  k_prep<<<dim3(64, 4), 512, 0, stream>>>(feat, wv, wr, b_red, b_val, A, sq, val);
  k_fused<<<dim3(128, 4), 512, 0, stream>>>(A, sq, val, feat, out);
}

// Round 3
// 154.700 us; speedup vs baseline: 1.2761x; 1.2761x over previous
//
#include <hip/hip_runtime.h>
#include <cstdint>
#include <cstddef>

typedef __attribute__((ext_vector_type(8))) short short8;
typedef __attribute__((ext_vector_type(4))) float f32x4;

#define MFMA16(a,b,c) __builtin_amdgcn_mfma_f32_16x16x32_bf16((a),(b),(c),0,0,0)

static __device__ __forceinline__ unsigned short f2bf(float f) {
  union { float f; unsigned u; } v; v.f = f;
  unsigned r = v.u + 0x7fffu + ((v.u >> 16) & 1u);
  return (unsigned short)(r >> 16);
}
static __device__ __forceinline__ float bf2f(unsigned short h) {
  union { unsigned u; float f; } v; v.u = ((unsigned)h) << 16;
  return v.f;
}

// ---------------- K0: weights f32 -> bf16 ----------------
__global__ __launch_bounds__(256) void k_wcvt(const float* __restrict__ w_val,
                                              const float* __restrict__ w_red,
                                              unsigned short* __restrict__ wv,
                                              unsigned short* __restrict__ wr) {
  int i = blockIdx.x * 256 + threadIdx.x;
  if (i < 65536) wv[i] = f2bf(w_val[i]);
  int j = i - 65536;
  if (j >= 0 && j < 8192) wr[j] = f2bf(w_red[j]);
}

// ---------------- K1: fused transpose + A/sq + val ----------------
__global__ __launch_bounds__(512) void k_prep(const float* __restrict__ feat,
                                              const unsigned short* __restrict__ wv,
                                              const unsigned short* __restrict__ wr,
                                              const float* __restrict__ b_red,
                                              const float* __restrict__ b_val,
                                              unsigned short* __restrict__ A,
                                              float* __restrict__ sq,
                                              unsigned short* __restrict__ val) {
  __shared__ unsigned short smT[64][264];  // 33 x 16B row stride (odd) -> conflict-free b128 reads
  __shared__ float sqp[2][64];
  const int t = threadIdx.x, w = t >> 6, lane = t & 63, a = lane & 15, g = lane >> 4;
  const int b = blockIdx.y, p0 = blockIdx.x * 64;
  const float* fb = feat + (size_t)b * 256 * 4096;
#pragma unroll
  for (int it = 0; it < 8; ++it) {
    int c0 = w * 4 + it * 32;
    const float* src = fb + (size_t)c0 * 4096 + p0 + lane;
    unsigned short u0 = f2bf(src[0]);
    unsigned short u1 = f2bf(src[4096]);
    unsigned short u2 = f2bf(src[8192]);
    unsigned short u3 = f2bf(src[12288]);
    uint2 pk;
    pk.x = u0 | ((unsigned)u1 << 16);
    pk.y = u2 | ((unsigned)u3 << 16);
    *(uint2*)&smT[lane][c0] = pk;
  }
  __syncthreads();

  f32x4 accv[2][4] = {};
  const int rs = w & 1, rms = w >> 1;
  f32x4 accr = {0, 0, 0, 0};
#pragma unroll
  for (int kk = 0; kk < 8; ++kk) {
    short8 bfr[4];
#pragma unroll
    for (int ms = 0; ms < 4; ++ms)
      bfr[ms] = *(const short8*)&smT[ms * 16 + a][kk * 32 + g * 8];
#pragma unroll
    for (int s = 0; s < 2; ++s) {
      short8 af = *(const short8*)&wv[(w * 32 + s * 16 + a) * 256 + kk * 32 + g * 8];
#pragma unroll
      for (int ms = 0; ms < 4; ++ms)
        accv[s][ms] = MFMA16(af, bfr[ms], accv[s][ms]);
    }
    short8 wrf = *(const short8*)&wr[(rs * 16 + a) * 256 + kk * 32 + g * 8];
    accr = MFMA16(bfr[rms], wrf, accr);
  }
#pragma unroll
  for (int s = 0; s < 2; ++s) {
    f32x4 bv = *(const f32x4*)&b_val[w * 32 + s * 16 + g * 4];
#pragma unroll
    for (int ms = 0; ms < 4; ++ms) {
#pragma unroll
      for (int r = 0; r < 4; ++r) {
        float v = accv[s][ms][r] + bv[r];
        v = v > 0.f ? v : 0.f;
        int o = w * 32 + s * 16 + g * 4 + r;
        val[((size_t)(b * 256 + o)) * 4096 + p0 + ms * 16 + a] = f2bf(v);
      }
    }
  }
  float bias = b_red[rs * 16 + a];
  float rsum[4];
  unsigned short* Ab = A + ((size_t)b * 4096 + p0 + rms * 16) * 32;
#pragma unroll
  for (int r = 0; r < 4; ++r) {
    float v = accr[r] + bias;
    v = v > 0.f ? v : 0.f;
    unsigned short h = f2bf(v);
    Ab[(g * 4 + r) * 32 + rs * 16 + a] = h;
    float vb = bf2f(h);
    rsum[r] = vb * vb;
  }
#pragma unroll
  for (int off = 1; off < 16; off <<= 1) {
#pragma unroll
    for (int r = 0; r < 4; ++r) rsum[r] += __shfl_xor(rsum[r], off, 64);
  }
  if (a == 0) {
#pragma unroll
    for (int r = 0; r < 4; ++r) sqp[rs][rms * 16 + g * 4 + r] = rsum[r];
  }
  __syncthreads();
  if (t < 64) sq[(size_t)b * 4096 + p0 + t] = sqp[0][t] + sqp[1][t];
}

// ---------------- K2: fused mask + (val @ mask) + residual ----------------
// 256 WGs (64 m-tiles of 64 x 4 b), 512 thr. Wave w: S-subtiles (nsub=w&3, msub=2*(w>>2)+h),
// GEMM2 rows c in [32w,32w+32). Software pipeline: loads(tt+1) issued before GEMM2(tt);
// lgkm-only barrier; NON-TEMPORAL mask/out stores so val stays L2-resident per XCD.
__global__ __launch_bounds__(512) void k_fused(const unsigned short* __restrict__ A,
                                               const float* __restrict__ sq,
                                               const unsigned short* __restrict__ val,
                                               const float* __restrict__ feat,
                                               float* __restrict__ dout) {
  __shared__ unsigned short ldsT[2][64][72];  // [buf][m][n], 9 x 16B row stride
  const int t = threadIdx.x, w = t >> 6, lane = t & 63, a = lane & 15, g = lane >> 4;
  const int nsub = w & 3, mh = w >> 2;
  // bijective XCD swizzle: 32 contiguous WGs per XCD; XCD pair {2b,2b+1} <-> batch b
  const int lin = blockIdx.x + (blockIdx.y << 6);
  const int swz = (lin & 7) * 32 + (lin >> 3);
  const int b = swz >> 6, m0 = (swz & 63) * 64;
  const unsigned short* Ab = A + (size_t)b * 4096 * 32;
  const float* sqb = sq + (size_t)b * 4096;
  const unsigned short* vb = val + ((size_t)b * 256 + w * 32) * 4096;
  float* maskout = dout + 4194304 + (size_t)b * 16777216;

  short8 am[2];
  float sqm[2];
  int mrow[2];
#pragma unroll
  for (int h = 0; h < 2; ++h) {
    mrow[h] = m0 + (2 * mh + h) * 16 + a;
    am[h] = *(const short8*)&Ab[(size_t)mrow[h] * 32 + g * 8];
    sqm[h] = sqb[mrow[h]];
  }
  f32x4 acc[2][4] = {};

  // pipeline registers (double-buffered)
  short8 an_c, an_n;
  f32x4 sqn_c, sqn_n;
  short8 vf_c[2][2], vf_n[2][2];
  float mk_c[2][4], mk_n[2][4];

  // ---- LOADS(0) ----
  an_c = *(const short8*)&Ab[(size_t)(nsub * 16 + a) * 32 + g * 8];
  sqn_c = *(const f32x4*)&sqb[nsub * 16 + g * 4];
#pragma unroll
  for (int cs = 0; cs < 2; ++cs)
#pragma unroll
    for (int ks = 0; ks < 2; ++ks)
      vf_c[cs][ks] = *(const short8*)&vb[(size_t)(cs * 16 + a) * 4096 + ks * 32 + g * 8];
  // ---- SMASK(0) + LDSWR(0) ----
  {
    f32x4 zero = {0, 0, 0, 0};
#pragma unroll
    for (int h = 0; h < 2; ++h) {
      f32x4 sfr = MFMA16(an_c, am[h], zero);
#pragma unroll
      for (int r = 0; r < 4; ++r) {
        float u = __expf(fmaf(2.f, sfr[r], -(sqn_c[r] + sqm[h])));
        float u2 = u * u;
        float pa = fmaf(u2, 2.0833333e-3f, -2.0833333e-2f);
        float pb = fmaf(u2, pa, 0.25f);
        mk_c[h][r] = fmaf(u, pb, 0.5f);
      }
      uint2 pk;
      pk.x = f2bf(mk_c[h][0]) | ((unsigned)f2bf(mk_c[h][1]) << 16);
      pk.y = f2bf(mk_c[h][2]) | ((unsigned)f2bf(mk_c[h][3]) << 16);
      *(uint2*)&ldsT[0][(2 * mh + h) * 16 + a][nsub * 16 + g * 4] = pk;
    }
  }
  asm volatile("s_waitcnt lgkmcnt(0)\n\ts_barrier" ::: "memory");

#pragma unroll 2
  for (int tt = 0; tt < 63; ++tt) {
    const int n0 = tt * 64, n1 = n0 + 64;
    const int buf = tt & 1;
    // ---- LOADS(tt+1): issue early, consumed after GEMM2 ----
    an_n = *(const short8*)&Ab[(size_t)(n1 + nsub * 16 + a) * 32 + g * 8];
    sqn_n = *(const f32x4*)&sqb[n1 + nsub * 16 + g * 4];
#pragma unroll
    for (int cs = 0; cs < 2; ++cs)
#pragma unroll
      for (int ks = 0; ks < 2; ++ks)
        vf_n[cs][ks] = *(const short8*)&vb[(size_t)(cs * 16 + a) * 4096 + n1 + ks * 32 + g * 8];
    // ---- GEMM2(tt) ----
#pragma unroll
    for (int ks = 0; ks < 2; ++ks) {
      short8 bfr[4];
#pragma unroll
      for (int ms = 0; ms < 4; ++ms)
        bfr[ms] = *(const short8*)&ldsT[buf][ms * 16 + a][ks * 32 + g * 8];
#pragma unroll
      for (int cs = 0; cs < 2; ++cs)
#pragma unroll
        for (int ms = 0; ms < 4; ++ms)
          acc[cs][ms] = MFMA16(vf_c[cs][ks], bfr[ms], acc[cs][ms]);
    }
    // ---- STORE(tt): non-temporal, bypass L2 pollution ----
#pragma unroll
    for (int h = 0; h < 2; ++h) {
      f32x4 v = {mk_c[h][0], mk_c[h][1], mk_c[h][2], mk_c[h][3]};
      __builtin_nontemporal_store(v, (f32x4*)&maskout[(size_t)mrow[h] * 4096 + n0 + nsub * 16 + g * 4]);
    }
    // ---- SMASK(tt+1) + LDSWR(tt+1) ----
    {
      f32x4 zero = {0, 0, 0, 0};
#pragma unroll
      for (int h = 0; h < 2; ++h) {
        f32x4 sfr = MFMA16(an_n, am[h], zero);
#pragma unroll
        for (int r = 0; r < 4; ++r) {
          float u = __expf(fmaf(2.f, sfr[r], -(sqn_n[r] + sqm[h])));
          float u2 = u * u;
          float pa = fmaf(u2, 2.0833333e-3f, -2.0833333e-2f);
          float pb = fmaf(u2, pa, 0.25f);
          mk_n[h][r] = fmaf(u, pb, 0.5f);
        }
        uint2 pk;
        pk.x = f2bf(mk_n[h][0]) | ((unsigned)f2bf(mk_n[h][1]) << 16);
        pk.y = f2bf(mk_n[h][2]) | ((unsigned)f2bf(mk_n[h][3]) << 16);
        *(uint2*)&ldsT[buf ^ 1][(2 * mh + h) * 16 + a][nsub * 16 + g * 4] = pk;
      }
    }
    asm volatile("s_waitcnt lgkmcnt(0)\n\ts_barrier" ::: "memory");
    // ---- rotate pipeline regs (free under unroll 2) ----
    an_c = an_n;
    sqn_c = sqn_n;
#pragma unroll
    for (int cs = 0; cs < 2; ++cs)
#pragma unroll
      for (int ks = 0; ks < 2; ++ks) vf_c[cs][ks] = vf_n[cs][ks];
#pragma unroll
    for (int h = 0; h < 2; ++h)
#pragma unroll
      for (int r = 0; r < 4; ++r) mk_c[h][r] = mk_n[h][r];
  }
  // ---- tail: GEMM2(63) + STORE(63) ----
  {
    const int n0 = 63 * 64;
#pragma unroll
    for (int ks = 0; ks < 2; ++ks) {
      short8 bfr[4];
#pragma unroll
      for (int ms = 0; ms < 4; ++ms)
        bfr[ms] = *(const short8*)&ldsT[1][ms * 16 + a][ks * 32 + g * 8];
#pragma unroll
      for (int cs = 0; cs < 2; ++cs)
#pragma unroll
        for (int ms = 0; ms < 4; ++ms)
          acc[cs][ms] = MFMA16(vf_c[cs][ks], bfr[ms], acc[cs][ms]);
    }
#pragma unroll
    for (int h = 0; h < 2; ++h) {
      f32x4 v = {mk_c[h][0], mk_c[h][1], mk_c[h][2], mk_c[h][3]};
      __builtin_nontemporal_store(v, (f32x4*)&maskout[(size_t)mrow[h] * 4096 + n0 + nsub * 16 + g * 4]);
    }
  }
  // ---- epilogue: out = acc + features (read-once/write-once -> nt) ----
  const float* fb = feat + (size_t)b * 256 * 4096;
  float* ob = dout + (size_t)b * 256 * 4096;
#pragma unroll
  for (int cs = 0; cs < 2; ++cs) {
#pragma unroll
    for (int ms = 0; ms < 4; ++ms) {
#pragma unroll
      for (int r = 0; r < 4; ++r) {
        int c = w * 32 + cs * 16 + g * 4 + r;
        int m = m0 + ms * 16 + a;
        size_t idx = (size_t)c * 4096 + m;
        float fv = __builtin_nontemporal_load(&fb[idx]);
        __builtin_nontemporal_store(acc[cs][ms][r] + fv, &ob[idx]);
      }
    }
  }
}

extern "C" void kernel_launch(void* const* d_in, const int* in_sizes, int n_in,
                              void* d_out, int out_size, void* d_ws, size_t ws_size,
                              hipStream_t stream) {
  const float* feat  = (const float*)d_in[0];
  const float* w_red = (const float*)d_in[1];
  const float* b_red = (const float*)d_in[2];
  const float* w_val = (const float*)d_in[3];
  const float* b_val = (const float*)d_in[4];
  float* out = (float*)d_out;
  char* ws = (char*)d_ws;
  unsigned short* A   = (unsigned short*)ws;               // 1,048,576 B
  float*          sq  = (float*)        (ws + 1048576);    //    65,536 B
  unsigned short* wv  = (unsigned short*)(ws + 1114112);   //   131,072 B
  unsigned short* wr  = (unsigned short*)(ws + 1245184);   //    16,384 B
  unsigned short* val = (unsigned short*)(ws + 1261568);   // 8,388,608 B

  k_wcvt<<<dim3(288), 256, 0, stream>>>(w_val, w_red, wv, wr);
  k_prep<<<dim3(64, 4), 512, 0, stream>>>(feat, wv, wr, b_red, b_val, A, sq, val);
  k_fused<<<dim3(64, 4), 512, 0, stream>>>(A, sq, val, feat, out);
}

// Round 4
// 142.576 us; speedup vs baseline: 1.3846x; 1.0850x over previous
//
#include <hip/hip_runtime.h>
#include <cstdint>
#include <cstddef>

typedef __attribute__((ext_vector_type(8))) short short8;
typedef __attribute__((ext_vector_type(4))) float f32x4;

#define MFMA16(a,b,c) __builtin_amdgcn_mfma_f32_16x16x32_bf16((a),(b),(c),0,0,0)

static __device__ __forceinline__ unsigned short f2bf(float f) {
  union { float f; unsigned u; } v; v.f = f;
  unsigned r = v.u + 0x7fffu + ((v.u >> 16) & 1u);
  return (unsigned short)(r >> 16);
}
static __device__ __forceinline__ float bf2f(unsigned short h) {
  union { unsigned u; float f; } v; v.u = ((unsigned)h) << 16;
  return v.f;
}

// ---------------- K0: weights f32 -> bf16 ----------------
__global__ __launch_bounds__(256) void k_wcvt(const float* __restrict__ w_val,
                                              const float* __restrict__ w_red,
                                              unsigned short* __restrict__ wv,
                                              unsigned short* __restrict__ wr) {
  int i = blockIdx.x * 256 + threadIdx.x;
  if (i < 65536) wv[i] = f2bf(w_val[i]);
  int j = i - 65536;
  if (j >= 0 && j < 8192) wr[j] = f2bf(w_red[j]);
}

// ---------------- K1: fused transpose + A/sq + val (p-tile 32, 2 WG/CU) ----------------
__global__ __launch_bounds__(512) void k_prep(const float* __restrict__ feat,
                                              const unsigned short* __restrict__ wv,
                                              const unsigned short* __restrict__ wr,
                                              const float* __restrict__ b_red,
                                              const float* __restrict__ b_val,
                                              unsigned short* __restrict__ A,
                                              float* __restrict__ sq,
                                              unsigned short* __restrict__ val) {
  __shared__ unsigned short smT[32][264];  // 33 x 16B row stride (odd) -> conflict-free b128 reads
  __shared__ float sqp[2][32];
  const int t = threadIdx.x, w = t >> 6, lane = t & 63, a = lane & 15, g = lane >> 4;
  const int b = blockIdx.y, p0 = blockIdx.x * 32;
  const float* fb = feat + (size_t)b * 256 * 4096;
  // stage feat tile: thread covers p = t&31, 4 consecutive c per iter
  {
    const int p = t & 31, cg = t >> 5;
#pragma unroll
    for (int it = 0; it < 4; ++it) {
      int c0 = cg * 4 + it * 64;
      const float* src = fb + (size_t)c0 * 4096 + p0 + p;
      unsigned short u0 = f2bf(src[0]);
      unsigned short u1 = f2bf(src[4096]);
      unsigned short u2 = f2bf(src[8192]);
      unsigned short u3 = f2bf(src[12288]);
      uint2 pk;
      pk.x = u0 | ((unsigned)u1 << 16);
      pk.y = u2 | ((unsigned)u3 << 16);
      *(uint2*)&smT[p][c0] = pk;
    }
  }
  __syncthreads();

  f32x4 accv[2][2] = {};
  const int rs = w & 1, rms = (w >> 1) & 1;
  f32x4 accr = {0, 0, 0, 0};
#pragma unroll
  for (int kk = 0; kk < 8; ++kk) {
    short8 bfr[2];
#pragma unroll
    for (int ms = 0; ms < 2; ++ms)
      bfr[ms] = *(const short8*)&smT[ms * 16 + a][kk * 32 + g * 8];
#pragma unroll
    for (int s = 0; s < 2; ++s) {
      short8 af = *(const short8*)&wv[(w * 32 + s * 16 + a) * 256 + kk * 32 + g * 8];
#pragma unroll
      for (int ms = 0; ms < 2; ++ms)
        accv[s][ms] = MFMA16(af, bfr[ms], accv[s][ms]);
    }
    if (w < 4) {
      short8 wrf = *(const short8*)&wr[(rs * 16 + a) * 256 + kk * 32 + g * 8];
      accr = MFMA16(bfr[rms], wrf, accr);
    }
  }
#pragma unroll
  for (int s = 0; s < 2; ++s) {
    f32x4 bv = *(const f32x4*)&b_val[w * 32 + s * 16 + g * 4];
#pragma unroll
    for (int ms = 0; ms < 2; ++ms) {
#pragma unroll
      for (int r = 0; r < 4; ++r) {
        float v = accv[s][ms][r] + bv[r];
        v = v > 0.f ? v : 0.f;
        int o = w * 32 + s * 16 + g * 4 + r;
        val[((size_t)(b * 256 + o)) * 4096 + p0 + ms * 16 + a] = f2bf(v);
      }
    }
  }
  if (w < 4) {
    float bias = b_red[rs * 16 + a];
    float rsum[4];
    unsigned short* Ab = A + ((size_t)b * 4096 + p0 + rms * 16) * 32;
#pragma unroll
    for (int r = 0; r < 4; ++r) {
      float v = accr[r] + bias;
      v = v > 0.f ? v : 0.f;
      unsigned short h = f2bf(v);
      Ab[(g * 4 + r) * 32 + rs * 16 + a] = h;
      float vb = bf2f(h);
      rsum[r] = vb * vb;
    }
#pragma unroll
    for (int off = 1; off < 16; off <<= 1) {
#pragma unroll
      for (int r = 0; r < 4; ++r) rsum[r] += __shfl_xor(rsum[r], off, 64);
    }
    if (a == 0) {
#pragma unroll
      for (int r = 0; r < 4; ++r) sqp[rs][rms * 16 + g * 4 + r] = rsum[r];
    }
  }
  __syncthreads();
  if (t < 32) sq[(size_t)b * 4096 + p0 + t] = sqp[0][t] + sqp[1][t];
}

// ---------------- K2: fused mask + (val @ mask) + residual ----------------
// 256 WGs (64 m-tiles of 64 x 4 b), 1024 thr (16 waves, 4/SIMD). Wave w: S-subtile
// (nsub=w&3, msub=w>>2), GEMM2 rows c in [16w,16w+16), mask-store rows [4w,4w+4).
// f32 mask staged in LDS -> 256B-contiguous nt row stores. lgkm-only barrier.
__global__ __launch_bounds__(1024) void k_fused(const unsigned short* __restrict__ A,
                                                const float* __restrict__ sq,
                                                const unsigned short* __restrict__ val,
                                                const float* __restrict__ feat,
                                                float* __restrict__ dout) {
  __shared__ unsigned short ldsT[2][64][72];  // bf16 [m][n] tile, 9 x 16B row stride
  __shared__ float ldsF[2][64][68];           // f32  [m][n] tile, 17 x 16B row stride
  const int t = threadIdx.x, w = t >> 6, lane = t & 63, a = lane & 15, g = lane >> 4;
  const int nsub = w & 3, msub = w >> 2;
  // bijective XCD swizzle: 32 contiguous WGs per XCD; XCD pair {2b,2b+1} <-> batch b
  const int lin = blockIdx.x + (blockIdx.y << 6);
  const int swz = (lin & 7) * 32 + (lin >> 3);
  const int b = swz >> 6, m0 = (swz & 63) * 64;
  const unsigned short* Ab = A + (size_t)b * 4096 * 32;
  const float* sqb = sq + (size_t)b * 4096;
  const unsigned short* vb = val + ((size_t)b * 256 + w * 16) * 4096;
  float* maskout = dout + 4194304 + (size_t)b * 16777216;

  const int mrow = m0 + msub * 16 + a;
  const short8 am = *(const short8*)&Ab[(size_t)mrow * 32 + g * 8];
  const float sqm = sqb[mrow];
  f32x4 acc[4] = {};
  const f32x4 zero = {0, 0, 0, 0};

  short8 vf_c[2], vf_n[2];

  // ---- prologue: S(0)+mask -> LDS[0]; vf(0) loads ----
  {
    short8 an0 = *(const short8*)&Ab[(size_t)(nsub * 16 + a) * 32 + g * 8];
    f32x4 sqn0 = *(const f32x4*)&sqb[nsub * 16 + g * 4];
    f32x4 sfr = MFMA16(an0, am, zero);
    f32x4 mkv;
#pragma unroll
    for (int r = 0; r < 4; ++r) {
      float u = __expf(fmaf(2.f, sfr[r], -(sqn0[r] + sqm)));
      float u2 = u * u;
      float pa = fmaf(u2, 2.0833333e-3f, -2.0833333e-2f);
      float pb = fmaf(u2, pa, 0.25f);
      mkv[r] = fmaf(u, pb, 0.5f);
    }
    uint2 pk;
    pk.x = f2bf(mkv[0]) | ((unsigned)f2bf(mkv[1]) << 16);
    pk.y = f2bf(mkv[2]) | ((unsigned)f2bf(mkv[3]) << 16);
    *(uint2*)&ldsT[0][msub * 16 + a][nsub * 16 + g * 4] = pk;
    *(f32x4*)&ldsF[0][msub * 16 + a][nsub * 16 + g * 4] = mkv;
  }
  vf_c[0] = *(const short8*)&vb[(size_t)a * 4096 + g * 8];
  vf_c[1] = *(const short8*)&vb[(size_t)a * 4096 + 32 + g * 8];
  asm volatile("s_waitcnt lgkmcnt(0)\n\ts_barrier" ::: "memory");

#pragma unroll 2
  for (int tt = 0; tt < 64; ++tt) {
    const int n0 = tt * 64, n1 = n0 + 64, buf = tt & 1;
    short8 an_n;
    f32x4 sqn_n;
    // ---- issue loads for tt+1 early ----
    if (tt < 63) {
      an_n = *(const short8*)&Ab[(size_t)(n1 + nsub * 16 + a) * 32 + g * 8];
      sqn_n = *(const f32x4*)&sqb[n1 + nsub * 16 + g * 4];
      vf_n[0] = *(const short8*)&vb[(size_t)a * 4096 + n1 + g * 8];
      vf_n[1] = *(const short8*)&vb[(size_t)a * 4096 + n1 + 32 + g * 8];
    }
    // ---- GEMM2(tt): acc[c,m] += val[c, n-tile] @ mask[m, n-tile]^T ----
#pragma unroll
    for (int ks = 0; ks < 2; ++ks) {
      short8 bfr[4];
#pragma unroll
      for (int ms = 0; ms < 4; ++ms)
        bfr[ms] = *(const short8*)&ldsT[buf][ms * 16 + a][ks * 32 + g * 8];
#pragma unroll
      for (int ms = 0; ms < 4; ++ms)
        acc[ms] = MFMA16(vf_c[ks], bfr[ms], acc[ms]);
    }
    // ---- mask rows [4w, 4w+4): 256B-contiguous nt stores from LDS ----
#pragma unroll
    for (int j = 0; j < 4; ++j) {
      float mv = ldsF[buf][w * 4 + j][lane];
      __builtin_nontemporal_store(mv, &maskout[(size_t)(m0 + w * 4 + j) * 4096 + n0 + lane]);
    }
    // ---- S(tt+1)+mask -> LDS[buf^1] ----
    if (tt < 63) {
      f32x4 sfr = MFMA16(an_n, am, zero);
      f32x4 mkv;
#pragma unroll
      for (int r = 0; r < 4; ++r) {
        float u = __expf(fmaf(2.f, sfr[r], -(sqn_n[r] + sqm)));
        float u2 = u * u;
        float pa = fmaf(u2, 2.0833333e-3f, -2.0833333e-2f);
        float pb = fmaf(u2, pa, 0.25f);
        mkv[r] = fmaf(u, pb, 0.5f);
      }
      uint2 pk;
      pk.x = f2bf(mkv[0]) | ((unsigned)f2bf(mkv[1]) << 16);
      pk.y = f2bf(mkv[2]) | ((unsigned)f2bf(mkv[3]) << 16);
      *(uint2*)&ldsT[buf ^ 1][msub * 16 + a][nsub * 16 + g * 4] = pk;
      *(f32x4*)&ldsF[buf ^ 1][msub * 16 + a][nsub * 16 + g * 4] = mkv;
    }
    asm volatile("s_waitcnt lgkmcnt(0)\n\ts_barrier" ::: "memory");
    vf_c[0] = vf_n[0];
    vf_c[1] = vf_n[1];
  }
  // ---- epilogue: out = acc + features ----
  const float* fb = feat + (size_t)b * 256 * 4096;
  float* ob = dout + (size_t)b * 256 * 4096;
#pragma unroll
  for (int ms = 0; ms < 4; ++ms) {
#pragma unroll
    for (int r = 0; r < 4; ++r) {
      int c = w * 16 + g * 4 + r;
      int m = m0 + ms * 16 + a;
      size_t idx = (size_t)c * 4096 + m;
      float fv = __builtin_nontemporal_load(&fb[idx]);
      __builtin_nontemporal_store(acc[ms][r] + fv, &ob[idx]);
    }
  }
}

extern "C" void kernel_launch(void* const* d_in, const int* in_sizes, int n_in,
                              void* d_out, int out_size, void* d_ws, size_t ws_size,
                              hipStream_t stream) {
  const float* feat  = (const float*)d_in[0];
  const float* w_red = (const float*)d_in[1];
  const float* b_red = (const float*)d_in[2];
  const float* w_val = (const float*)d_in[3];
  const float* b_val = (const float*)d_in[4];
  float* out = (float*)d_out;
  char* ws = (char*)d_ws;
  unsigned short* A   = (unsigned short*)ws;               // 1,048,576 B
  float*          sq  = (float*)        (ws + 1048576);    //    65,536 B
  unsigned short* wv  = (unsigned short*)(ws + 1114112);   //   131,072 B
  unsigned short* wr  = (unsigned short*)(ws + 1245184);   //    16,384 B
  unsigned short* val = (unsigned short*)(ws + 1261568);   // 8,388,608 B

  k_wcvt<<<dim3(288), 256, 0, stream>>>(w_val, w_red, wv, wr);
  k_prep<<<dim3(128, 4), 512, 0, stream>>>(feat, wv, wr, b_red, b_val, A, sq, val);
  k_fused<<<dim3(64, 4), 1024, 0, stream>>>(A, sq, val, feat, out);
}